// Round 8
// baseline (208.712 us; speedup 1.0000x reference)
//
#include <hip/hip_runtime.h>

#define HIDDEN 128
#define NBUCKETS 20

typedef unsigned int uint32;
typedef unsigned short u16;
typedef unsigned long long u64;
typedef __attribute__((ext_vector_type(8))) short bf16x8;
typedef __attribute__((ext_vector_type(4))) float f32x4;

__device__ __forceinline__ u16 f32_to_bf16(float f) {
    uint32 u = __float_as_uint(f);
    return (u16)((u + 0x7fffu + ((u >> 16) & 1u)) >> 16);
}
__device__ __forceinline__ float bf_lo(uint32 u) { return __uint_as_float(u << 16); }
__device__ __forceinline__ float bf_hi(uint32 u) { return __uint_as_float(u & 0xffff0000u); }

// k1: W1T transpose+convert, zero cnt, de_dot.
__global__ void prep_kernel(const float* __restrict__ W1, u16* __restrict__ W1T,
                            int* __restrict__ cnt, int n_nodes,
                            const float* __restrict__ table,
                            const float* __restrict__ W2,
                            float* __restrict__ de_dot) {
    int idx = blockIdx.x * 256 + threadIdx.x;
    int n = idx >> 7, k = idx & 127;
    int srow = (n < 128) ? k : (128 + k);
    W1T[idx] = f32_to_bf16(W1[srow * HIDDEN + (n & 127)]);
    for (int i = idx; i < n_nodes; i += 32768) cnt[i] = 0;
    if (blockIdx.x == 0 && threadIdx.x < NBUCKETS) {
        float a = 0.f;
        for (int kk = 0; kk < HIDDEN; ++kk)
            a = fmaf(table[threadIdx.x * HIDDEN + kk], W2[HIDDEN + kk], a);
        de_dot[threadIdx.x] = a;
    }
}

// k2: fused degree-histogram + MFMA GEMM (one 16-row tile/block).
__global__ __launch_bounds__(256)
void gemm_count_kernel(const float* __restrict__ x, const u16* __restrict__ W1T,
                       const int* __restrict__ tgt, int* __restrict__ cnt,
                       u16* __restrict__ y16, u16* __restrict__ z16,
                       u16* __restrict__ x16, int n_nodes, int n_edges) {
    __shared__ bf16x8 lds_a[16][16];
    __shared__ u16 lds_c[4][16][72];

    int tid = threadIdx.x;
    int e = blockIdx.x * 256 + tid;
    if (e < n_edges) atomicAdd(&cnt[tgt[e]], 1);

    int row_base = blockIdx.x * 16;
    if (row_base >= n_nodes) return;

    {
        int row = tid >> 4, c = tid & 15;
        int node = row_base + row;
        bf16x8 a = {};
        if (node < n_nodes) {
            const float4* xp = (const float4*)(x + (size_t)node * HIDDEN + c * 8);
            float4 v0 = xp[0], v1 = xp[1];
            a[0] = (short)f32_to_bf16(v0.x); a[1] = (short)f32_to_bf16(v0.y);
            a[2] = (short)f32_to_bf16(v0.z); a[3] = (short)f32_to_bf16(v0.w);
            a[4] = (short)f32_to_bf16(v1.x); a[5] = (short)f32_to_bf16(v1.y);
            a[6] = (short)f32_to_bf16(v1.z); a[7] = (short)f32_to_bf16(v1.w);
            *(bf16x8*)(x16 + (size_t)node * HIDDEN + c * 8) = a;
        }
        lds_a[c][row] = a;
    }
    __syncthreads();

    int wave = tid >> 6, lane = tid & 63;
    int m = lane & 15, kb = lane >> 4;

    bf16x8 afrag[4];
#pragma unroll
    for (int ks = 0; ks < 4; ++ks) afrag[ks] = lds_a[ks * 4 + kb][m];

#pragma unroll
    for (int ci = 0; ci < 4; ++ci) {
        int col = wave * 64 + ci * 16 + m;
        const u16* bp = W1T + (size_t)col * HIDDEN + kb * 8;
        f32x4 acc = {0.f, 0.f, 0.f, 0.f};
#pragma unroll
        for (int ks = 0; ks < 4; ++ks) {
            bf16x8 b = *(const bf16x8*)(bp + ks * 32);
            acc = __builtin_amdgcn_mfma_f32_16x16x32_bf16(afrag[ks], b, acc, 0, 0, 0);
        }
#pragma unroll
        for (int e2 = 0; e2 < 4; ++e2)
            lds_c[wave][kb * 4 + e2][ci * 16 + m] = f32_to_bf16(acc[e2]);
    }
    __syncthreads();

    {
        int r = lane >> 2, q = lane & 3;
        const u16* src = &lds_c[wave][r][q * 16];
        bf16x8 c0 = *(const bf16x8*)(src);
        bf16x8 c1 = *(const bf16x8*)(src + 8);
        int node = row_base + r;
        int colg = wave * 64 + q * 16;
        if (node < n_nodes) {
            u16* dst = (colg < HIDDEN) ? (y16 + (size_t)node * HIDDEN + colg)
                                       : (z16 + (size_t)node * HIDDEN + colg - HIDDEN);
            *(bf16x8*)dst = c0;
            *(bf16x8*)(dst + 8) = c1;
        }
    }
}

// k3: per-block exclusive prescan of cnt + block totals; re-zero cnt (cursor reuse).
__global__ void scan_blocks_kernel(int* __restrict__ cnt,
                                   int* __restrict__ prescan,
                                   int* __restrict__ partial,
                                   int n_nodes) {
    __shared__ int sh[256];
    int t = threadIdx.x;
    int i = blockIdx.x * 256 + t;
    int v = (i < n_nodes) ? cnt[i] : 0;
    sh[t] = v;
    __syncthreads();
    for (int d = 1; d < 256; d <<= 1) {
        int add = (t >= d) ? sh[t - d] : 0;
        __syncthreads();
        sh[t] += add;
        __syncthreads();
    }
    if (i < n_nodes) { prescan[i] = sh[t] - v; cnt[i] = 0; }
    if (t == 255) partial[blockIdx.x] = sh[t];
}

// k4: exclusive scan of block totals (nb <= 256).
__global__ void scan_partials_kernel(int* __restrict__ partial, int nb) {
    __shared__ int sh[256];
    int t = threadIdx.x;
    int v = (t < nb) ? partial[t] : 0;
    sh[t] = v;
    __syncthreads();
    for (int d = 1; d < 256; d <<= 1) {
        int add = (t >= d) ? sh[t - d] : 0;
        __syncthreads();
        sh[t] += add;
        __syncthreads();
    }
    if (t < nb) partial[t] = sh[t] - v;
}

// k5: scatter edges into CSR order; record packs {s:20, t:20, bucket:5}.
__global__ void scatter_kernel(const int* __restrict__ edge_index,
                               const int* __restrict__ distances,
                               const int* __restrict__ prescan,
                               const int* __restrict__ partial,
                               int* __restrict__ cnt,
                               u64* __restrict__ csr_st,
                               int n_edges) {
    int e = blockIdx.x * blockDim.x + threadIdx.x;
    if (e >= n_edges) return;
    int s = edge_index[e];
    int t = edge_index[n_edges + e];
    u64 bk = (u64)(distances[e] / 50);
    int base = prescan[t] + partial[t >> 8];
    int pos = atomicAdd(&cnt[t], 1);
    csr_st[base + pos] = (u64)(uint32)s | ((u64)(uint32)t << 20) | (bk << 40);
}

// k6: edge-parallel attention logits. One LANE per edge: full 128-feature
// dot computed per-lane (no cross-lane ops); sigmoid/exp amortized to
// wave-wide instructions. CSR order keeps z-gathers L1-run-resident.
__global__ __launch_bounds__(256)
void logit_kernel(const u64* __restrict__ csr_st,
                  const u16* __restrict__ y16,
                  const u16* __restrict__ z16,
                  const float* __restrict__ W2,
                  const float* __restrict__ de_dot,
                  float* __restrict__ csr_att,
                  int n_edges) {
    __shared__ float w_lds[HIDDEN];
    __shared__ float d_lds[NBUCKETS];
    int tid = threadIdx.x;
    if (tid < HIDDEN) w_lds[tid] = W2[tid];
    else if (tid < HIDDEN + NBUCKETS) d_lds[tid - HIDDEN] = de_dot[tid - HIDDEN];
    __syncthreads();

    int i = blockIdx.x * 256 + tid;
    int ic = (i < n_edges) ? i : (n_edges - 1);
    u64 rec = csr_st[ic];
    int s = (int)(rec & 0xFFFFF);
    int t = (int)((rec >> 20) & 0xFFFFF);
    float ded = d_lds[(int)(rec >> 40)];

    const uint4* yr = (const uint4*)(y16 + (size_t)s * HIDDEN);
    const uint4* zr = (const uint4*)(z16 + (size_t)t * HIDDEN);
    float p0 = 0.f, p1 = 0.f;
#pragma unroll 4
    for (int c = 0; c < 16; ++c) {
        uint4 yv = yr[c];
        uint4 zv = zr[c];
        const float4* wp = (const float4*)&w_lds[c * 8];
        float4 w0 = wp[0], w1 = wp[1];
        float h;
        h = bf_lo(yv.x) + bf_lo(zv.x); h = fmaxf(h, 0.2f * h); p0 = fmaf(h, w0.x, p0);
        h = bf_hi(yv.x) + bf_hi(zv.x); h = fmaxf(h, 0.2f * h); p1 = fmaf(h, w0.y, p1);
        h = bf_lo(yv.y) + bf_lo(zv.y); h = fmaxf(h, 0.2f * h); p0 = fmaf(h, w0.z, p0);
        h = bf_hi(yv.y) + bf_hi(zv.y); h = fmaxf(h, 0.2f * h); p1 = fmaf(h, w0.w, p1);
        h = bf_lo(yv.z) + bf_lo(zv.z); h = fmaxf(h, 0.2f * h); p0 = fmaf(h, w1.x, p0);
        h = bf_hi(yv.z) + bf_hi(zv.z); h = fmaxf(h, 0.2f * h); p1 = fmaf(h, w1.y, p1);
        h = bf_lo(yv.w) + bf_lo(zv.w); h = fmaxf(h, 0.2f * h); p0 = fmaf(h, w1.z, p0);
        h = bf_hi(yv.w) + bf_hi(zv.w); h = fmaxf(h, 0.2f * h); p1 = fmaf(h, w1.w, p1);
    }
    float v = p0 + p1 + ded;
    float att = __expf(1.f / (1.f + __expf(-v)));
    if (i < n_edges) csr_att[i] = att;
}

// k7: one wave per node: x-gather accumulate + normalize + relu only.
__global__ void aggregate_kernel(const u16* __restrict__ x16,
                                 const u64* __restrict__ csr_st,
                                 const float* __restrict__ csr_att,
                                 const int* __restrict__ prescan,
                                 const int* __restrict__ partial,
                                 const int* __restrict__ cnt,
                                 float* __restrict__ out,
                                 int n_nodes) {
    int lane = threadIdx.x & 63;
    int t = blockIdx.x * (blockDim.x >> 6) + (threadIdx.x >> 6);
    if (t >= n_nodes) return;

    int base = prescan[t] + partial[t >> 8];
    int deg = cnt[t];
    const uint32* __restrict__ xp = (const uint32*)x16;

    float acc0 = 0.f, acc1 = 0.f, attsum = 0.f;

    for (int b = 0; b < deg; b += 64) {
        int nb = min(64, deg - b);
        int s_l = 0;
        float a_l = 0.f;
        if (lane < nb) {
            s_l = (int)(csr_st[base + b + lane] & 0xFFFFF);
            a_l = csr_att[base + b + lane];
        }
        attsum += a_l;
        int j = 0;
        for (; j + 4 <= nb; j += 4) {
            int sA = __shfl(s_l, j, 64);
            int sB = __shfl(s_l, j + 1, 64);
            int sC = __shfl(s_l, j + 2, 64);
            int sD = __shfl(s_l, j + 3, 64);
            float aA = __shfl(a_l, j, 64);
            float aB = __shfl(a_l, j + 1, 64);
            float aC = __shfl(a_l, j + 2, 64);
            float aD = __shfl(a_l, j + 3, 64);
            uint32 xa = xp[(size_t)sA * 64 + lane];
            uint32 xb = xp[(size_t)sB * 64 + lane];
            uint32 xc = xp[(size_t)sC * 64 + lane];
            uint32 xd = xp[(size_t)sD * 64 + lane];
            acc0 = fmaf(aA, bf_lo(xa), acc0);
            acc1 = fmaf(aA, bf_hi(xa), acc1);
            acc0 = fmaf(aB, bf_lo(xb), acc0);
            acc1 = fmaf(aB, bf_hi(xb), acc1);
            acc0 = fmaf(aC, bf_lo(xc), acc0);
            acc1 = fmaf(aC, bf_hi(xc), acc1);
            acc0 = fmaf(aD, bf_lo(xd), acc0);
            acc1 = fmaf(aD, bf_hi(xd), acc1);
        }
        for (; j < nb; ++j) {
            int sA = __shfl(s_l, j, 64);
            float aA = __shfl(a_l, j, 64);
            uint32 xa = xp[(size_t)sA * 64 + lane];
            acc0 = fmaf(aA, bf_lo(xa), acc0);
            acc1 = fmaf(aA, bf_hi(xa), acc1);
        }
    }
#pragma unroll
    for (int off = 32; off > 0; off >>= 1) attsum += __shfl_xor(attsum, off, 64);
    float inv = 1.f / (attsum + 1e-6f);
    float2 o;
    o.x = fmaxf(acc0 * inv, 0.f);
    o.y = fmaxf(acc1 * inv, 0.f);
    *(float2*)(out + (size_t)t * HIDDEN + lane * 2) = o;
}

static inline size_t align16(size_t v) { return (v + 15) & ~(size_t)15; }

extern "C" void kernel_launch(void* const* d_in, const int* in_sizes, int n_in,
                              void* d_out, int out_size, void* d_ws, size_t ws_size,
                              hipStream_t stream) {
    const float* x          = (const float*)d_in[0];
    const int*   edge_index = (const int*)d_in[1];
    const int*   distances  = (const int*)d_in[2];
    const float* W1         = (const float*)d_in[3];
    const float* W2         = (const float*)d_in[4];
    const float* table      = (const float*)d_in[5];

    int n_nodes = in_sizes[0] / HIDDEN;
    int n_edges = in_sizes[1] / 2;
    float* out = (float*)d_out;

    // Workspace layout (16B-aligned sections)
    char* p = (char*)d_ws;
    int* cnt      = (int*)p;                 p += align16((size_t)n_nodes * 4);
    int* prescan  = (int*)p;                 p += align16((size_t)n_nodes * 4);
    int* partial  = (int*)p;                 p += align16(256 * 4);
    u64* csr_st   = (u64*)p;                 p += align16((size_t)n_edges * 8);
    float* csr_att = (float*)p;              p += align16((size_t)n_edges * 4);
    float* de_dot  = (float*)p;              p += align16(32 * 4);
    u16* W1T       = (u16*)p;                p += align16(256 * HIDDEN * 2);
    u16* y16       = (u16*)p;                p += align16((size_t)n_nodes * HIDDEN * 2);
    u16* z16       = (u16*)p;                p += align16((size_t)n_nodes * HIDDEN * 2);
    u16* x16       = (u16*)p;

    const int* tgt = edge_index + n_edges;

    prep_kernel<<<128, 256, 0, stream>>>(W1, W1T, cnt, n_nodes, table, W2, de_dot);

    int ntiles = (n_nodes + 15) / 16;
    int eblocks = (n_edges + 255) / 256;
    int gblocks = (ntiles > eblocks) ? ntiles : eblocks;
    gemm_count_kernel<<<gblocks, 256, 0, stream>>>(x, W1T, tgt, cnt,
                                                   y16, z16, x16, n_nodes, n_edges);

    int nb = (n_nodes + 255) / 256;
    scan_blocks_kernel<<<nb, 256, 0, stream>>>(cnt, prescan, partial, n_nodes);
    scan_partials_kernel<<<1, 256, 0, stream>>>(partial, nb);

    scatter_kernel<<<eblocks, 256, 0, stream>>>(
        edge_index, distances, prescan, partial, cnt, csr_st, n_edges);

    logit_kernel<<<eblocks, 256, 0, stream>>>(
        csr_st, y16, z16, W2, de_dot, csr_att, n_edges);

    const int waves_per_block = 4;
    int ablocks = (n_nodes + waves_per_block - 1) / waves_per_block;
    aggregate_kernel<<<ablocks, 64 * waves_per_block, 0, stream>>>(
        x16, csr_st, csr_att, prescan, partial, cnt, out, n_nodes);
}

// Round 9
// 197.464 us; speedup vs baseline: 1.0570x; 1.0570x over previous
//
#include <hip/hip_runtime.h>

#define HIDDEN 128
#define NBUCKETS 20

typedef unsigned int uint32;
typedef unsigned short u16;
typedef unsigned long long u64;
typedef __attribute__((ext_vector_type(8))) short bf16x8;
typedef __attribute__((ext_vector_type(4))) float f32x4;

__device__ __forceinline__ u16 f32_to_bf16(float f) {
    uint32 u = __float_as_uint(f);
    return (u16)((u + 0x7fffu + ((u >> 16) & 1u)) >> 16);
}
__device__ __forceinline__ float bf_lo(uint32 u) { return __uint_as_float(u << 16); }
__device__ __forceinline__ float bf_hi(uint32 u) { return __uint_as_float(u & 0xffff0000u); }

// k1: W1T transpose+convert, zero cnt, de_dot.
__global__ void prep_kernel(const float* __restrict__ W1, u16* __restrict__ W1T,
                            int* __restrict__ cnt, int n_nodes,
                            const float* __restrict__ table,
                            const float* __restrict__ W2,
                            float* __restrict__ de_dot) {
    int idx = blockIdx.x * 256 + threadIdx.x;
    int n = idx >> 7, k = idx & 127;
    int srow = (n < 128) ? k : (128 + k);
    W1T[idx] = f32_to_bf16(W1[srow * HIDDEN + (n & 127)]);
    for (int i = idx; i < n_nodes; i += 32768) cnt[i] = 0;
    if (blockIdx.x == 0 && threadIdx.x < NBUCKETS) {
        float a = 0.f;
        for (int kk = 0; kk < HIDDEN; ++kk)
            a = fmaf(table[threadIdx.x * HIDDEN + kk], W2[HIDDEN + kk], a);
        de_dot[threadIdx.x] = a;
    }
}

// k2: fused degree-histogram + MFMA GEMM (one 16-row tile/block).
__global__ __launch_bounds__(256)
void gemm_count_kernel(const float* __restrict__ x, const u16* __restrict__ W1T,
                       const int* __restrict__ tgt, int* __restrict__ cnt,
                       u16* __restrict__ y16, u16* __restrict__ z16,
                       u16* __restrict__ x16, int n_nodes, int n_edges) {
    __shared__ bf16x8 lds_a[16][16];
    __shared__ u16 lds_c[4][16][72];

    int tid = threadIdx.x;
    int e = blockIdx.x * 256 + tid;
    if (e < n_edges) atomicAdd(&cnt[tgt[e]], 1);

    int row_base = blockIdx.x * 16;
    if (row_base >= n_nodes) return;

    {
        int row = tid >> 4, c = tid & 15;
        int node = row_base + row;
        bf16x8 a = {};
        if (node < n_nodes) {
            const float4* xp = (const float4*)(x + (size_t)node * HIDDEN + c * 8);
            float4 v0 = xp[0], v1 = xp[1];
            a[0] = (short)f32_to_bf16(v0.x); a[1] = (short)f32_to_bf16(v0.y);
            a[2] = (short)f32_to_bf16(v0.z); a[3] = (short)f32_to_bf16(v0.w);
            a[4] = (short)f32_to_bf16(v1.x); a[5] = (short)f32_to_bf16(v1.y);
            a[6] = (short)f32_to_bf16(v1.z); a[7] = (short)f32_to_bf16(v1.w);
            *(bf16x8*)(x16 + (size_t)node * HIDDEN + c * 8) = a;
        }
        lds_a[c][row] = a;
    }
    __syncthreads();

    int wave = tid >> 6, lane = tid & 63;
    int m = lane & 15, kb = lane >> 4;

    bf16x8 afrag[4];
#pragma unroll
    for (int ks = 0; ks < 4; ++ks) afrag[ks] = lds_a[ks * 4 + kb][m];

#pragma unroll
    for (int ci = 0; ci < 4; ++ci) {
        int col = wave * 64 + ci * 16 + m;
        const u16* bp = W1T + (size_t)col * HIDDEN + kb * 8;
        f32x4 acc = {0.f, 0.f, 0.f, 0.f};
#pragma unroll
        for (int ks = 0; ks < 4; ++ks) {
            bf16x8 b = *(const bf16x8*)(bp + ks * 32);
            acc = __builtin_amdgcn_mfma_f32_16x16x32_bf16(afrag[ks], b, acc, 0, 0, 0);
        }
#pragma unroll
        for (int e2 = 0; e2 < 4; ++e2)
            lds_c[wave][kb * 4 + e2][ci * 16 + m] = f32_to_bf16(acc[e2]);
    }
    __syncthreads();

    {
        int r = lane >> 2, q = lane & 3;
        const u16* src = &lds_c[wave][r][q * 16];
        bf16x8 c0 = *(const bf16x8*)(src);
        bf16x8 c1 = *(const bf16x8*)(src + 8);
        int node = row_base + r;
        int colg = wave * 64 + q * 16;
        if (node < n_nodes) {
            u16* dst = (colg < HIDDEN) ? (y16 + (size_t)node * HIDDEN + colg)
                                       : (z16 + (size_t)node * HIDDEN + colg - HIDDEN);
            *(bf16x8*)dst = c0;
            *(bf16x8*)(dst + 8) = c1;
        }
    }
}

// k3: per-block exclusive prescan of cnt + block totals; re-zero cnt (cursor reuse).
__global__ void scan_blocks_kernel(int* __restrict__ cnt,
                                   int* __restrict__ prescan,
                                   int* __restrict__ partial,
                                   int n_nodes) {
    __shared__ int sh[256];
    int t = threadIdx.x;
    int i = blockIdx.x * 256 + t;
    int v = (i < n_nodes) ? cnt[i] : 0;
    sh[t] = v;
    __syncthreads();
    for (int d = 1; d < 256; d <<= 1) {
        int add = (t >= d) ? sh[t - d] : 0;
        __syncthreads();
        sh[t] += add;
        __syncthreads();
    }
    if (i < n_nodes) { prescan[i] = sh[t] - v; cnt[i] = 0; }
    if (t == 255) partial[blockIdx.x] = sh[t];
}

// k4: exclusive scan of block totals (nb <= 256).
__global__ void scan_partials_kernel(int* __restrict__ partial, int nb) {
    __shared__ int sh[256];
    int t = threadIdx.x;
    int v = (t < nb) ? partial[t] : 0;
    sh[t] = v;
    __syncthreads();
    for (int d = 1; d < 256; d <<= 1) {
        int add = (t >= d) ? sh[t - d] : 0;
        __syncthreads();
        sh[t] += add;
        __syncthreads();
    }
    if (t < nb) partial[t] = sh[t] - v;
}

// k5: scatter edges into CSR order; record packs {ded_f32:32, s:32}.
__global__ void scatter_kernel(const int* __restrict__ edge_index,
                               const int* __restrict__ distances,
                               const int* __restrict__ prescan,
                               const int* __restrict__ partial,
                               const float* __restrict__ de_dot,
                               int* __restrict__ cnt,
                               u64* __restrict__ csr_sd,
                               int n_edges) {
    int e = blockIdx.x * blockDim.x + threadIdx.x;
    if (e >= n_edges) return;
    int s = edge_index[e];
    int t = edge_index[n_edges + e];
    float ded = de_dot[distances[e] / 50];
    int base = prescan[t] + partial[t >> 8];
    int pos = atomicAdd(&cnt[t], 1);
    csr_sd[base + pos] = ((u64)__float_as_uint(ded) << 32) | (uint32)s;
}

// k6: fused per-node attention+aggregation, 16-edge batched LDS-transpose
// logit reduction (no per-edge butterfly, transcendentals amortized 16x).
__global__ __launch_bounds__(256)
void aggregate_kernel(const u16* __restrict__ x16,
                      const u16* __restrict__ y16,
                      const u16* __restrict__ z16,
                      const float* __restrict__ W2,
                      const u64* __restrict__ csr_sd,
                      const int* __restrict__ prescan,
                      const int* __restrict__ partial,
                      const int* __restrict__ cnt,
                      float* __restrict__ out,
                      int n_nodes) {
    __shared__ float lds_p[4][16][68];   // [wave][edge][lane col + pad] : 17.4 KB
    int wave = threadIdx.x >> 6, lane = threadIdx.x & 63;
    int t = blockIdx.x * 4 + wave;
    if (t >= n_nodes) return;

    int base = prescan[t] + partial[t >> 8];
    int deg = cnt[t];
    const uint32* __restrict__ yp = (const uint32*)y16;
    const uint32* __restrict__ xp = (const uint32*)x16;

    uint32 zv = ((const uint32*)z16)[(size_t)t * 64 + lane];
    float z0 = bf_lo(zv), z1 = bf_hi(zv);
    float2 wv = *(const float2*)(W2 + lane * 2);
    float (*P)[68] = lds_p[wave];

    float acc0 = 0.f, acc1 = 0.f, attsum = 0.f;

    for (int b = 0; b < deg; b += 64) {
        int nb = min(64, deg - b);
        int s_l = 0; float ded_l = 0.f;
        if (lane < nb) {
            uint2 rec = *(const uint2*)(csr_sd + base + b + lane);
            s_l = (int)rec.x;
            ded_l = __uint_as_float(rec.y);
        }
        for (int sb = 0; sb < nb; sb += 16) {
            int c16 = min(16, nb - sb);
            uint32 xreg[16];
            // Phase A: per-edge 2-feature partial -> LDS[j][lane]; x row -> regs.
            // All loads independent across j -> deep ILP latency hiding.
#pragma unroll
            for (int j = 0; j < 16; ++j) {
                if (j >= c16) break;
                int sj = __shfl(s_l, sb + j, 64);
                uint32 yv = yp[(size_t)sj * 64 + lane];
                xreg[j] = xp[(size_t)sj * 64 + lane];
                float h0 = bf_lo(yv) + z0; h0 = fmaxf(h0, 0.2f * h0);
                float h1 = bf_hi(yv) + z1; h1 = fmaxf(h1, 0.2f * h1);
                P[j][lane] = fmaf(h0, wv.x, h1 * wv.y);
            }
            // Phase B: lane L reduces edge (L&15) over cols (L>>4)*16..+16,
            // then 2-step cross-group reduce; sigmoid/exp once per 16 edges.
            const float4* pr = (const float4*)(P[lane & 15] + ((lane >> 4) << 4));
            float4 q0 = pr[0], q1 = pr[1], q2 = pr[2], q3 = pr[3];
            float s4 = ((q0.x + q0.y) + (q0.z + q0.w))
                     + ((q1.x + q1.y) + (q1.z + q1.w))
                     + ((q2.x + q2.y) + (q2.z + q2.w))
                     + ((q3.x + q3.y) + (q3.z + q3.w));
            s4 += __shfl_xor(s4, 16, 64);
            s4 += __shfl_xor(s4, 32, 64);
            float ded_e = __shfl(ded_l, sb + (lane & 15), 64);
            float att = __expf(1.f / (1.f + __expf(-(s4 + ded_e))));
            att = ((lane & 15) < c16) ? att : 0.f;
            attsum += (lane < 16) ? att : 0.f;
            // Phase C: broadcast att, accumulate stashed x.
#pragma unroll
            for (int j = 0; j < 16; ++j) {
                if (j >= c16) break;
                float aj = __shfl(att, j, 64);
                acc0 = fmaf(aj, bf_lo(xreg[j]), acc0);
                acc1 = fmaf(aj, bf_hi(xreg[j]), acc1);
            }
        }
    }
#pragma unroll
    for (int off = 32; off > 0; off >>= 1) attsum += __shfl_xor(attsum, off, 64);
    float inv = 1.f / (attsum + 1e-6f);
    float2 o;
    o.x = fmaxf(acc0 * inv, 0.f);
    o.y = fmaxf(acc1 * inv, 0.f);
    *(float2*)(out + (size_t)t * HIDDEN + lane * 2) = o;
}

static inline size_t align16(size_t v) { return (v + 15) & ~(size_t)15; }

extern "C" void kernel_launch(void* const* d_in, const int* in_sizes, int n_in,
                              void* d_out, int out_size, void* d_ws, size_t ws_size,
                              hipStream_t stream) {
    const float* x          = (const float*)d_in[0];
    const int*   edge_index = (const int*)d_in[1];
    const int*   distances  = (const int*)d_in[2];
    const float* W1         = (const float*)d_in[3];
    const float* W2         = (const float*)d_in[4];
    const float* table      = (const float*)d_in[5];

    int n_nodes = in_sizes[0] / HIDDEN;
    int n_edges = in_sizes[1] / 2;
    float* out = (float*)d_out;

    // Workspace layout (16B-aligned sections)
    char* p = (char*)d_ws;
    int* cnt      = (int*)p;                 p += align16((size_t)n_nodes * 4);
    int* prescan  = (int*)p;                 p += align16((size_t)n_nodes * 4);
    int* partial  = (int*)p;                 p += align16(256 * 4);
    u64* csr_sd   = (u64*)p;                 p += align16((size_t)n_edges * 8);
    float* de_dot  = (float*)p;              p += align16(32 * 4);
    u16* W1T       = (u16*)p;                p += align16(256 * HIDDEN * 2);
    u16* y16       = (u16*)p;                p += align16((size_t)n_nodes * HIDDEN * 2);
    u16* z16       = (u16*)p;                p += align16((size_t)n_nodes * HIDDEN * 2);
    u16* x16       = (u16*)p;

    const int* tgt = edge_index + n_edges;

    prep_kernel<<<128, 256, 0, stream>>>(W1, W1T, cnt, n_nodes, table, W2, de_dot);

    int ntiles = (n_nodes + 15) / 16;
    int eblocks = (n_edges + 255) / 256;
    int gblocks = (ntiles > eblocks) ? ntiles : eblocks;
    gemm_count_kernel<<<gblocks, 256, 0, stream>>>(x, W1T, tgt, cnt,
                                                   y16, z16, x16, n_nodes, n_edges);

    int nb = (n_nodes + 255) / 256;
    scan_blocks_kernel<<<nb, 256, 0, stream>>>(cnt, prescan, partial, n_nodes);
    scan_partials_kernel<<<1, 256, 0, stream>>>(partial, nb);

    scatter_kernel<<<eblocks, 256, 0, stream>>>(
        edge_index, distances, prescan, partial, de_dot, cnt, csr_sd, n_edges);

    int ablocks = (n_nodes + 3) / 4;
    aggregate_kernel<<<ablocks, 256, 0, stream>>>(
        x16, y16, z16, W2, csr_sd, prescan, partial, cnt, out, n_nodes);
}